// Round 10
// baseline (1801.096 us; speedup 1.0000x reference)
//
#include <hip/hip_runtime.h>
#include <hip/hip_bf16.h>
#include <math.h>

// GAT 2-layer. Round 19: src-sorted scatter-accumulate aggregation.
// kg1 (86.7us, FETCH 240MB, 42% L2 hit on a 25.6MB gather set) is replaced
// by kg1s: each block owns a 128-dst bucket with f32 LDS accumulators
// (64KB) and walks its edges SORTED BY SRC — all resident blocks sweep src
// ascending together, so the device-wide live h1b window fits per-XCD L2.
// Weight computation keeps the 16-edge/4-head shuffle prepass. kg2s same
// structure (8KB acc). CSR (rowptr/colidx/kcsr) deleted; chain is
// kcnt(fused in kgemmc, dst>>7) -> kofs -> kbkt2 (packed src<<7|dl u32,
// fixed-stride buckets) -> ksrt (per-bucket LDS sort by src). h2p packing
// reverted (R18 neutral). Falsifier: kg1s FETCH >= 200MB kills the theory.

typedef unsigned short u16;
typedef unsigned int u32;
typedef __attribute__((ext_vector_type(8))) short bf16x8;
typedef __attribute__((ext_vector_type(4))) float f32x4;

#define BSTRIDE2 2560   // u32 slots per 128-dst bucket (mean 2048, +11 sigma)

__device__ __forceinline__ float eluf(float v) { return v > 0.f ? v : expm1f(v); }
__device__ __forceinline__ u16 f2bf(float f) {
    u32 u = __float_as_uint(f);
    u += 0x7fff + ((u >> 16) & 1);          // RNE
    return (u16)(u >> 16);
}
__device__ __forceinline__ float bf2f(u16 u) {
    return __uint_as_float(((u32)u) << 16);
}
// exp(leaky02(e)) = exp2(e * (e>=0 ? log2e : 0.2*log2e))
__device__ __forceinline__ float expleaky(float e) {
    float m = e >= 0.f ? 1.44269504f : 0.28853901f;
    return exp2f(e * m);
}

// ---------------- ksetup: W1 frag swizzle | W2 prep ------------------------
__global__ __launch_bounds__(256) void ksetup(
    const float* __restrict__ W1, const float* __restrict__ W2,
    const float* __restrict__ ats2, const float* __restrict__ atd2,
    u16* __restrict__ w1fh, u16* __restrict__ w1fl,
    float* __restrict__ u, float* __restrict__ v, u16* __restrict__ w2tb)
{
    const int b = blockIdx.x, tid = threadIdx.x;
    if (b < 64) {
        int idx = b * 256 + tid;
        int j = idx & 7, l = (idx >> 3) & 63, q = (idx >> 9) & 3, ct = idx >> 11;
        int k = q * 32 + (l >> 4) * 8 + j;
        int n = ct * 16 + (l & 15);
        float w = W1[k * 128 + n];
        u16 hv = f2bf(w);
        w1fh[idx] = hv;
        w1fl[idx] = f2bf(w - bf2f(hv));
    } else {
        if (tid < 128) {
            float su = 0.f, sv = 0.f;
            #pragma unroll
            for (int j = 0; j < 16; ++j) {
                float w = W2[tid * 16 + j];
                su = fmaf(w, ats2[j], su);
                sv = fmaf(w, atd2[j], sv);
                w2tb[j * 128 + tid] = f2bf(w);
            }
            u[tid] = su; v[tid] = sv;
        }
    }
}

// ---------------- kgemmc: heterogeneous kcnt(dst>>7) + persistent GEMM -----
#define REPW 40   // u16 per repack row (80 B)
__global__ __launch_bounds__(256) void kgemmc(
    const float* __restrict__ x, const u16* __restrict__ w1fh,
    const u16* __restrict__ w1fl,
    const float* __restrict__ att_s, const float* __restrict__ att_d,
    u16* __restrict__ h1b, float* __restrict__ as1, float* __restrict__ ad1,
    int N, int GB,
    const int* __restrict__ ei, int* __restrict__ M,
    int E, int NEB, int NBKT, int KB)
{
    __shared__ u16 rep[4][16 * REPW];
    __shared__ int cnt[1024];
    const int tid = threadIdx.x;
    const int b = blockIdx.x;

    if (b < KB) {
        // ---- kcnt role: 128-dst bucket histogram ----
        for (int q = tid; q < 1024; q += 256) cnt[q] = 0;
        __syncthreads();
        const int e0 = b * 2048 + tid;
        int dd[8];
        #pragma unroll
        for (int k = 0; k < 8; ++k) {
            int e = e0 + 256 * k;
            dd[k] = (e < E) ? ei[E + e] : -1;
        }
        #pragma unroll
        for (int k = 0; k < 8; ++k)
            if (dd[k] >= 0) atomicAdd(&cnt[dd[k] >> 7], 1);
        __syncthreads();
        for (int q = tid; q < NBKT; q += 256) M[q * NEB + b] = cnt[q];
        return;
    }

    const int g = b - KB;
    const int wv = tid >> 6, lane = tid & 63;
    const int m = lane & 15, quad = lane >> 4;
    const int h = wv;                        // head handled by this wave

    bf16x8 bh[2][4], bl[2][4];
    #pragma unroll
    for (int sub = 0; sub < 2; ++sub) {
        #pragma unroll
        for (int q = 0; q < 4; ++q) {
            const int off = (((2 * h + sub) * 4 + q) * 64 + lane) * 8;
            bh[sub][q] = *(const bf16x8*)&w1fh[off];
            bl[sub][q] = *(const bf16x8*)&w1fl[off];
        }
    }
    #pragma unroll
    for (int sub = 0; sub < 2; ++sub) {
        #pragma unroll
        for (int q = 0; q < 4; ++q) {
            asm volatile("" : "+v"(bh[sub][q]));
            asm volatile("" : "+v"(bl[sub][q]));
        }
    }

    const float cs0 = att_s[h * 32 + m];
    const float cs1 = att_s[h * 32 + 16 + m];
    const float cd0 = att_d[h * 32 + m];
    const float cd1 = att_d[h * 32 + 16 + m];

    u16* myrep = rep[wv];
    const int ntile = (N + 15) >> 4;

    for (int t = g; t < ntile; t += GB) {
        const int r0 = t << 4;
        int arow = r0 + m;
        if (arow >= N) arow = N - 1;
        const float* xr = &x[(size_t)arow * 128 + quad * 8];

        bf16x8 ah[4], al[4];
        #pragma unroll
        for (int q = 0; q < 4; ++q) {
            float4 f0 = *(const float4*)&xr[q * 32];
            float4 f1 = *(const float4*)&xr[q * 32 + 4];
            float fv[8] = {f0.x, f0.y, f0.z, f0.w, f1.x, f1.y, f1.z, f1.w};
            union { u16 us[8]; bf16x8 v; } hh, lu;
            #pragma unroll
            for (int j = 0; j < 8; ++j) {
                u16 hvv = f2bf(fv[j]);
                hh.us[j] = hvv;
                lu.us[j] = f2bf(fv[j] - bf2f(hvv));
            }
            ah[q] = hh.v; al[q] = lu.v;
        }

        f32x4 acc[2];
        #pragma unroll
        for (int sub = 0; sub < 2; ++sub) {
            f32x4 a = {0.f, 0.f, 0.f, 0.f};
            #pragma unroll
            for (int q = 0; q < 4; ++q) {
                a = __builtin_amdgcn_mfma_f32_16x16x32_bf16(ah[q], bh[sub][q], a, 0, 0, 0);
                a = __builtin_amdgcn_mfma_f32_16x16x32_bf16(al[q], bh[sub][q], a, 0, 0, 0);
                a = __builtin_amdgcn_mfma_f32_16x16x32_bf16(ah[q], bl[sub][q], a, 0, 0, 0);
            }
            acc[sub] = a;
        }

        float sp[4], dp[4];
        #pragma unroll
        for (int r = 0; r < 4; ++r) {
            sp[r] = fmaf(acc[0][r], cs0, acc[1][r] * cs1);
            dp[r] = fmaf(acc[0][r], cd0, acc[1][r] * cd1);
        }
        #pragma unroll
        for (int r = 0; r < 4; ++r) {
            sp[r] += __shfl_xor(sp[r], 1); sp[r] += __shfl_xor(sp[r], 2);
            sp[r] += __shfl_xor(sp[r], 4); sp[r] += __shfl_xor(sp[r], 8);
            dp[r] += __shfl_xor(dp[r], 1); dp[r] += __shfl_xor(dp[r], 2);
            dp[r] += __shfl_xor(dp[r], 4); dp[r] += __shfl_xor(dp[r], 8);
        }
        if (m == 0) {
            #pragma unroll
            for (int r = 0; r < 4; ++r) {
                int rr = r0 + quad * 4 + r;
                if (rr < N) {
                    as1[rr * 4 + h] = sp[r];
                    ad1[rr * 4 + h] = dp[r];
                }
            }
        }

        #pragma unroll
        for (int sub = 0; sub < 2; ++sub) {
            #pragma unroll
            for (int r = 0; r < 4; ++r)
                myrep[(quad * 4 + r) * REPW + sub * 16 + m] = f2bf(acc[sub][r]);
        }
        __asm__ __volatile__("s_waitcnt lgkmcnt(0)" ::: "memory");
        __builtin_amdgcn_sched_barrier(0);
        const int rr = lane >> 2, cc = lane & 3;
        uint4 vv = *(const uint4*)&myrep[rr * REPW + cc * 8];
        const int grow = r0 + rr;
        if (grow < N)
            *(uint4*)&h1b[(size_t)grow * 128 + h * 32 + cc * 8] = vv;
    }
}

// ---------------- kofs: per-bucket exclusive scan over blocks --------------
__global__ __launch_bounds__(256) void kofs(
    int* __restrict__ M, int* __restrict__ tot, int NEB)
{
    __shared__ int lds[256];
    const int bkt = blockIdx.x, t = threadIdx.x;
    int carry = 0;
    const int rounds = (NEB + 255) / 256;
    for (int r = 0; r < rounds; ++r) {
        int idx = r * 256 + t;
        int v = (idx < NEB) ? M[bkt * NEB + idx] : 0;
        lds[t] = v;
        __syncthreads();
        for (int off = 1; off < 256; off <<= 1) {
            int y = (t >= off) ? lds[t - off] : 0;
            __syncthreads();
            lds[t] += y;
            __syncthreads();
        }
        if (idx < NEB) M[bkt * NEB + idx] = carry + lds[t] - v;
        carry += lds[255];
        __syncthreads();
    }
    if (t == 0) tot[bkt] = carry;
}

// ---------------- kbkt2: LDS-staged bucket scatter, packed u32 -------------
// st word = (src<<7) | dstLocal. Fixed-stride ebuf regions per bucket.
__global__ __launch_bounds__(256) void kbkt2(
    const int* __restrict__ ei, const int* __restrict__ M,
    u32* __restrict__ ebuf, int E, int NEB, int NBKT)
{
    __shared__ int cnt[1024], lofs[1024], cur[1024], boff[1024];
    __shared__ u32 st[2048];
    __shared__ int gp[2048];
    __shared__ int sscan[256];
    const int b = blockIdx.x, t = threadIdx.x;
    for (int q = t; q < 1024; q += 256) { cnt[q] = 0; cur[q] = 0; }
    __syncthreads();
    const int e0 = b * 2048 + t;
    int dd[8], ss[8];
    #pragma unroll
    for (int k = 0; k < 8; ++k) {
        int e = e0 + 256 * k;
        if (e < E) { dd[k] = ei[E + e]; ss[k] = ei[e]; } else dd[k] = -1;
    }
    #pragma unroll
    for (int k = 0; k < 8; ++k)
        if (dd[k] >= 0) atomicAdd(&cnt[dd[k] >> 7], 1);
    for (int q = t; q < NBKT; q += 256) boff[q] = q * BSTRIDE2 + M[q * NEB + b];
    __syncthreads();
    // exclusive scan of cnt[1024] -> lofs (4 elements per thread)
    int a0 = cnt[4 * t], a1 = cnt[4 * t + 1], a2 = cnt[4 * t + 2], a3 = cnt[4 * t + 3];
    int s = a0 + a1 + a2 + a3;
    sscan[t] = s;
    __syncthreads();
    for (int off = 1; off < 256; off <<= 1) {
        int y = (t >= off) ? sscan[t - off] : 0;
        __syncthreads();
        sscan[t] += y;
        __syncthreads();
    }
    int run = sscan[t] - s;
    lofs[4 * t] = run; run += a0;
    lofs[4 * t + 1] = run; run += a1;
    lofs[4 * t + 2] = run; run += a2;
    lofs[4 * t + 3] = run;
    __syncthreads();
    #pragma unroll
    for (int k = 0; k < 8; ++k) {
        if (dd[k] >= 0) {
            int bkt = dd[k] >> 7;
            int lr = atomicAdd(&cur[bkt], 1);
            int pos = lofs[bkt] + lr;
            st[pos] = ((u32)ss[k] << 7) | (u32)(dd[k] & 127);
            gp[pos] = boff[bkt] + lr;
        }
    }
    __syncthreads();
    const int nv = min(2048, E - b * 2048);
    for (int i = t; i < nv; i += 256)
        ebuf[gp[i]] = st[i];
}

// ---------------- ksrt: per-bucket LDS sort by src (key = word>>14) --------
__global__ __launch_bounds__(256) void ksrt(
    u32* __restrict__ ebuf, const int* __restrict__ tot)
{
    __shared__ int hist[1024], lofs[1024], cur[1024];
    __shared__ int sscan[256];
    __shared__ u32 st[BSTRIDE2], srt[BSTRIDE2];
    const int b = blockIdx.x, t = threadIdx.x;
    const int ne = tot[b];
    const int base = b * BSTRIDE2;
    for (int q = t; q < 1024; q += 256) hist[q] = 0;
    __syncthreads();
    for (int i = t; i < ne; i += 256) {
        u32 w = ebuf[base + i];
        st[i] = w;
        atomicAdd(&hist[w >> 14], 1);
    }
    __syncthreads();
    int a0 = hist[4 * t], a1 = hist[4 * t + 1], a2 = hist[4 * t + 2], a3 = hist[4 * t + 3];
    int s = a0 + a1 + a2 + a3;
    sscan[t] = s;
    __syncthreads();
    for (int off = 1; off < 256; off <<= 1) {
        int y = (t >= off) ? sscan[t - off] : 0;
        __syncthreads();
        sscan[t] += y;
        __syncthreads();
    }
    int run = sscan[t] - s;
    lofs[4 * t] = run; cur[4 * t] = run; run += a0;
    lofs[4 * t + 1] = run; cur[4 * t + 1] = run; run += a1;
    lofs[4 * t + 2] = run; cur[4 * t + 2] = run; run += a2;
    lofs[4 * t + 3] = run; cur[4 * t + 3] = run;
    __syncthreads();
    for (int i = t; i < ne; i += 256) {
        u32 w = st[i];
        int p = atomicAdd(&cur[w >> 14], 1);
        srt[p] = w;
    }
    __syncthreads();
    for (int i = t; i < ne; i += 256)
        ebuf[base + i] = srt[i];
}

// ---------------- KG1S: scatter-accumulate layer-1 aggregation -------------
// Block = 128-dst bucket. acc[128][128] f32 in LDS. Edges sorted by src.
__global__ __launch_bounds__(512) void kg1s(
    const u32* __restrict__ ebuf, const int* __restrict__ tot,
    const u16* __restrict__ h1b, const float* __restrict__ as1,
    const float* __restrict__ ad1, const float* __restrict__ b1,
    const float* __restrict__ u, const float* __restrict__ v,
    u16* __restrict__ x2b, float* __restrict__ as2, float* __restrict__ ad2,
    int N)
{
    __shared__ float acc[16384];     // [dl][ch] 64 KB
    __shared__ float sden[512];      // [dl][h]
    __shared__ float ad1loc[512];    // [dl][h]
    const int bkt = blockIdx.x, t = threadIdx.x;
    const int wv = t >> 6, l = t & 63;
    for (int q = t; q < 16384; q += 512) acc[q] = 0.f;
    sden[t] = 0.f;
    ad1loc[t] = ad1[(size_t)bkt * 512 + t];
    __syncthreads();

    const int ne = tot[bkt];
    const int base = bkt * BSTRIDE2;
    const int chunk = (ne + 7) >> 3;
    const int e0w = min(ne, wv * chunk);
    const int e1w = min(ne, e0w + chunk);
    const int eA = l >> 2, hA = l & 3, h = l >> 4;
    const int c2 = 2 * l;

    for (int i = e0w; i < e1w; i += 16) {
        const int nb = min(16, e1w - i);
        int ii = i + eA;
        int iic = ii < e1w ? ii : e0w;
        u32 ewA = ebuf[base + iic];
        int sA2 = (int)(ewA >> 7), dlA = (int)(ewA & 127u);
        float wA = expleaky(as1[sA2 * 4 + hA] + ad1loc[dlA * 4 + hA]);
        wA = (ii < e1w) ? wA : 0.f;
        atomicAdd(&sden[dlA * 4 + hA], wA);
        int e = 0;
        for (; e + 8 <= nb; e += 8) {
            u32 ew0 = __shfl(ewA, (e + 0) << 2);
            u32 ew1 = __shfl(ewA, (e + 1) << 2);
            u32 ew2 = __shfl(ewA, (e + 2) << 2);
            u32 ew3 = __shfl(ewA, (e + 3) << 2);
            u32 ew4 = __shfl(ewA, (e + 4) << 2);
            u32 ew5 = __shfl(ewA, (e + 5) << 2);
            u32 ew6 = __shfl(ewA, (e + 6) << 2);
            u32 ew7 = __shfl(ewA, (e + 7) << 2);
            u32 v0 = *(const u32*)&h1b[((size_t)(ew0 >> 7) << 7) + c2];
            u32 v1 = *(const u32*)&h1b[((size_t)(ew1 >> 7) << 7) + c2];
            u32 v2 = *(const u32*)&h1b[((size_t)(ew2 >> 7) << 7) + c2];
            u32 v3 = *(const u32*)&h1b[((size_t)(ew3 >> 7) << 7) + c2];
            u32 v4 = *(const u32*)&h1b[((size_t)(ew4 >> 7) << 7) + c2];
            u32 v5 = *(const u32*)&h1b[((size_t)(ew5 >> 7) << 7) + c2];
            u32 v6 = *(const u32*)&h1b[((size_t)(ew6 >> 7) << 7) + c2];
            u32 v7 = *(const u32*)&h1b[((size_t)(ew7 >> 7) << 7) + c2];
            float w0 = __shfl(wA, ((e + 0) << 2) + h);
            float w1 = __shfl(wA, ((e + 1) << 2) + h);
            float w2 = __shfl(wA, ((e + 2) << 2) + h);
            float w3 = __shfl(wA, ((e + 3) << 2) + h);
            float w4 = __shfl(wA, ((e + 4) << 2) + h);
            float w5 = __shfl(wA, ((e + 5) << 2) + h);
            float w6 = __shfl(wA, ((e + 6) << 2) + h);
            float w7 = __shfl(wA, ((e + 7) << 2) + h);
            int b0 = (int)(ew0 & 127u) * 128 + c2;
            int b1i = (int)(ew1 & 127u) * 128 + c2;
            int b2i = (int)(ew2 & 127u) * 128 + c2;
            int b3i = (int)(ew3 & 127u) * 128 + c2;
            int b4i = (int)(ew4 & 127u) * 128 + c2;
            int b5i = (int)(ew5 & 127u) * 128 + c2;
            int b6i = (int)(ew6 & 127u) * 128 + c2;
            int b7i = (int)(ew7 & 127u) * 128 + c2;
            atomicAdd(&acc[b0], w0 * bf2f((u16)v0));
            atomicAdd(&acc[b0 + 1], w0 * bf2f((u16)(v0 >> 16)));
            atomicAdd(&acc[b1i], w1 * bf2f((u16)v1));
            atomicAdd(&acc[b1i + 1], w1 * bf2f((u16)(v1 >> 16)));
            atomicAdd(&acc[b2i], w2 * bf2f((u16)v2));
            atomicAdd(&acc[b2i + 1], w2 * bf2f((u16)(v2 >> 16)));
            atomicAdd(&acc[b3i], w3 * bf2f((u16)v3));
            atomicAdd(&acc[b3i + 1], w3 * bf2f((u16)(v3 >> 16)));
            atomicAdd(&acc[b4i], w4 * bf2f((u16)v4));
            atomicAdd(&acc[b4i + 1], w4 * bf2f((u16)(v4 >> 16)));
            atomicAdd(&acc[b5i], w5 * bf2f((u16)v5));
            atomicAdd(&acc[b5i + 1], w5 * bf2f((u16)(v5 >> 16)));
            atomicAdd(&acc[b6i], w6 * bf2f((u16)v6));
            atomicAdd(&acc[b6i + 1], w6 * bf2f((u16)(v6 >> 16)));
            atomicAdd(&acc[b7i], w7 * bf2f((u16)v7));
            atomicAdd(&acc[b7i + 1], w7 * bf2f((u16)(v7 >> 16)));
        }
        for (; e < nb; ++e) {
            u32 ew = __shfl(ewA, e << 2);
            u32 vv = *(const u32*)&h1b[((size_t)(ew >> 7) << 7) + c2];
            float w = __shfl(wA, (e << 2) + h);
            int bi = (int)(ew & 127u) * 128 + c2;
            atomicAdd(&acc[bi], w * bf2f((u16)vv));
            atomicAdd(&acc[bi + 1], w * bf2f((u16)(vv >> 16)));
        }
    }
    __syncthreads();

    // finalize: 16 dsts per wave
    for (int j = 0; j < 16; ++j) {
        const int dl = wv * 16 + j;
        const int d = bkt * 128 + dl;
        if (d >= N) break;
        u32 hd = *(const u32*)&h1b[((size_t)d << 7) + c2];
        float wself = expleaky(as1[d * 4 + h] + ad1loc[dl * 4 + h]);
        float accx = acc[dl * 128 + c2] + wself * bf2f((u16)hd);
        float accy = acc[dl * 128 + c2 + 1] + wself * bf2f((u16)(hd >> 16));
        float denv = sden[dl * 4 + h] + wself;
        float inv = 1.f / denv;
        float2 bv = *(const float2*)&b1[c2];
        float x2a = eluf(fmaf(accx, inv, bv.x));
        float x2c = eluf(fmaf(accy, inv, bv.y));
        u32 pk = ((u32)f2bf(x2c) << 16) | (u32)f2bf(x2a);
        *(u32*)&x2b[((size_t)d << 7) + c2] = pk;
        float2 uv = *(const float2*)&u[c2];
        float2 vv2 = *(const float2*)&v[c2];
        float sA = fmaf(x2a, uv.x, x2c * uv.y);
        float sB = fmaf(x2a, vv2.x, x2c * vv2.y);
        #pragma unroll
        for (int mm = 1; mm < 64; mm <<= 1) {
            sA += __shfl_xor(sA, mm);
            sB += __shfl_xor(sB, mm);
        }
        if (l == 0) { as2[d] = sA; ad2[d] = sB; }
    }
}

// ---------------- KH2: h2 = x2 @ W2 via MFMA (bf16 out) --------------------
__global__ __launch_bounds__(256) void kh2(
    const u16* __restrict__ x2b, const u16* __restrict__ w2tb,
    u16* __restrict__ h2b, int N)
{
    const int wv = threadIdx.x >> 6, lane = threadIdx.x & 63;
    const int n0 = blockIdx.x * 64 + wv * 16;
    if (n0 >= N) return;
    const int m = lane & 15;
    const int kq = lane >> 4;
    bf16x8 bfr[4];
    #pragma unroll
    for (int q = 0; q < 4; ++q)
        bfr[q] = *(const bf16x8*)&w2tb[m * 128 + q * 32 + kq * 8];

    int ar = n0 + m;
    if (ar >= N) ar = N - 1;
    const u16* arow = &x2b[((size_t)ar << 7) + kq * 8];
    f32x4 acc = {0.f, 0.f, 0.f, 0.f};
    #pragma unroll
    for (int q = 0; q < 4; ++q) {
        bf16x8 af = *(const bf16x8*)&arow[q * 32];
        acc = __builtin_amdgcn_mfma_f32_16x16x32_bf16(af, bfr[q], acc, 0, 0, 0);
    }
    #pragma unroll
    for (int r = 0; r < 4; ++r) {
        int rr = n0 + kq * 4 + r;
        if (rr < N) h2b[((size_t)rr << 4) + m] = f2bf(acc[r]);
    }
}

// ---------------- KG2S: scatter-accumulate layer-2 aggregation -------------
// Block = 128-dst bucket. acc2[128][16] f32 (8KB). 8 edges/wave-iter.
__global__ __launch_bounds__(256) void kg2s(
    const u32* __restrict__ ebuf, const int* __restrict__ tot,
    const u16* __restrict__ h2b, const float* __restrict__ as2,
    const float* __restrict__ ad2, const float* __restrict__ b2,
    float* __restrict__ out, int N)
{
    __shared__ float acc2[2048];    // [dl][ch]
    __shared__ float den2[128];
    __shared__ float ad2loc[128];
    const int bkt = blockIdx.x, t = threadIdx.x;
    const int wv = t >> 6, l = t & 63;
    for (int q = t; q < 2048; q += 256) acc2[q] = 0.f;
    if (t < 128) {
        den2[t] = 0.f;
        ad2loc[t] = ad2[(size_t)bkt * 128 + t];
    }
    __syncthreads();

    const int ne = tot[bkt];
    const int base = bkt * BSTRIDE2;
    const int chunk = (ne + 3) >> 2;
    const int e0w = min(ne, wv * chunk);
    const int e1w = min(ne, e0w + chunk);
    const int ep = l >> 3, p = l & 7;

    for (int i = e0w; i < e1w; i += 8) {
        int ii = i + ep;
        int iic = ii < e1w ? ii : e0w;
        u32 ew = ebuf[base + iic];
        int s = (int)(ew >> 7), dl = (int)(ew & 127u);
        float w = expleaky(as2[s] + ad2loc[dl]);
        w = (ii < e1w) ? w : 0.f;
        u32 hv = *(const u32*)&h2b[((size_t)s << 4) + 2 * p];
        atomicAdd(&acc2[dl * 16 + 2 * p], w * bf2f((u16)hv));
        atomicAdd(&acc2[dl * 16 + 2 * p + 1], w * bf2f((u16)(hv >> 16)));
        if (p == 0) atomicAdd(&den2[dl], w);
    }
    __syncthreads();

    // finalize: 8 dsts per wave-iter, 4 iters per wave
    for (int j = 0; j < 4; ++j) {
        const int dl = wv * 32 + j * 8 + ep;
        const int d = bkt * 128 + dl;
        if (d < N) {
            float wself = expleaky(as2[d] + ad2loc[dl]);
            u32 hd = *(const u32*)&h2b[((size_t)d << 4) + 2 * p];
            float a0 = acc2[dl * 16 + 2 * p] + wself * bf2f((u16)hd);
            float a1 = acc2[dl * 16 + 2 * p + 1] + wself * bf2f((u16)(hd >> 16));
            float dv = den2[dl] + wself;
            float2 ov = {a0 / dv + b2[2 * p], a1 / dv + b2[2 * p + 1]};
            *(float2*)&out[((size_t)d << 4) + 2 * p] = ov;
        }
    }
}

extern "C" void kernel_launch(void* const* d_in, const int* in_sizes, int n_in,
                              void* d_out, int out_size, void* d_ws, size_t ws_size,
                              hipStream_t stream) {
    const float* x    = (const float*)d_in[0];
    const int*   ei   = (const int*)d_in[1];
    const float* W1   = (const float*)d_in[2];
    const float* ats1 = (const float*)d_in[3];
    const float* atd1 = (const float*)d_in[4];
    const float* b1   = (const float*)d_in[5];
    const float* W2   = (const float*)d_in[6];
    const float* ats2 = (const float*)d_in[7];
    const float* atd2 = (const float*)d_in[8];
    const float* b2   = (const float*)d_in[9];
    float* out = (float*)d_out;
    const int N = in_sizes[0] / 128;
    const int E = in_sizes[1] / 2;

    const int NEB  = (E + 2047) / 2048;             // edge blocks (782)
    const int NBKT = (N + 127) >> 7;                // 128-dst buckets (782)

    u16* h1b   = (u16*)d_ws;                        // 128N
    u16* x2b   = h1b + (size_t)N * 128;             // 128N
    u16* h2b   = x2b + (size_t)N * 128;             // 16N
    u16* w2tb  = h2b + (size_t)N * 16;              // 2048
    u16* w1fh  = w2tb + 2048;                       // 16384
    u16* w1fl  = w1fh + 16384;                      // 16384
    float* as1 = (float*)(w1fl + 16384);            // 4N
    float* ad1 = as1 + (size_t)N * 4;               // 4N
    float* as2 = ad1 + (size_t)N * 4;               // N
    float* ad2 = as2 + N;                           // N
    float* u   = ad2 + N;                           // 128
    float* v   = u + 128;                           // 128
    u32* ebuf  = (u32*)(v + 128);                   // NBKT*BSTRIDE2 (8 MB)
    int* M     = (int*)(ebuf + (size_t)NBKT * BSTRIDE2); // NBKT*NEB (2.45 MB)
    int* tot   = M + (size_t)NBKT * NEB;            // NBKT

    const int ntile = (N + 15) / 16;
    const int GB = (ntile + 3) / 4;                 // GEMM blocks (4 tiles each)
    const int KB = NEB;                             // kcnt blocks

    hipLaunchKernelGGL(ksetup, dim3(65), dim3(256), 0, stream,
                       W1, W2, ats2, atd2, w1fh, w1fl, u, v, w2tb);
    hipLaunchKernelGGL(kgemmc, dim3(KB + GB), dim3(256), 0, stream,
                       x, w1fh, w1fl, ats1, atd1, h1b, as1, ad1, N, GB,
                       ei, M, E, NEB, NBKT, KB);
    hipLaunchKernelGGL(kofs, dim3(NBKT), dim3(256), 0, stream, M, tot, NEB);
    hipLaunchKernelGGL(kbkt2, dim3(NEB), dim3(256), 0, stream,
                       ei, M, ebuf, E, NEB, NBKT);
    hipLaunchKernelGGL(ksrt, dim3(NBKT), dim3(256), 0, stream, ebuf, tot);
    hipLaunchKernelGGL(kg1s, dim3(NBKT), dim3(512), 0, stream,
                       ebuf, tot, h1b, as1, ad1, b1, u, v,
                       x2b, as2, ad2, N);
    hipLaunchKernelGGL(kh2, dim3((N + 63) / 64), dim3(256), 0, stream,
                       x2b, w2tb, h2b, N);
    hipLaunchKernelGGL(kg2s, dim3(NBKT), dim3(256), 0, stream,
                       ebuf, tot, h2b, as2, ad2, b2, out, N);
}